// Round 3
// baseline (852.711 us; speedup 1.0000x reference)
//
#include <hip/hip_runtime.h>
#include <hip/hip_bf16.h>

#define D 128
#define CAP 40

typedef __attribute__((ext_vector_type(8))) short bf16x8;
typedef __attribute__((ext_vector_type(4))) float f32x4;

__device__ __forceinline__ void atomAddF(float* p, float v) { unsafeAtomicAdd(p, v); }

__device__ __forceinline__ unsigned short f2bf(float f) {
    __hip_bfloat16 h = __float2bfloat16(f);
    return *reinterpret_cast<unsigned short*>(&h);
}
__device__ __forceinline__ float bf2f(unsigned int u16) {
    unsigned int x = u16 << 16;
    return *reinterpret_cast<float*>(&x);
}

// ---------------- cast fp32 -> bf16, 4 elems/thread ----------------
__global__ void cast_bf16(const float* __restrict__ in, unsigned short* __restrict__ out, long n4) {
    long i = (long)blockIdx.x * blockDim.x + threadIdx.x;
    if (i >= n4) return;
    float4 v = ((const float4*)in)[i];
    ushort4 o;
    o.x = f2bf(v.x); o.y = f2bf(v.y); o.z = f2bf(v.z); o.w = f2bf(v.w);
    ((ushort4*)out)[i] = o;
}

// ---------------- weights: cast + transpose (Wt[n*128+k] = W[k*128+n]) ----------------
__global__ void prep_weights(const float* __restrict__ Wra, const float* __restrict__ Wrg,
                             const float* __restrict__ Wrt, const float* __restrict__ Wroot_t,
                             const float* __restrict__ Wroot_a, const float* __restrict__ Wroot_g,
                             const float* __restrict__ ba, const float* __restrict__ bg,
                             unsigned short* __restrict__ Wt_adj, unsigned short* __restrict__ Wt_g,
                             unsigned short* __restrict__ Wt_t, unsigned short* __restrict__ Wt_root_t,
                             unsigned short* __restrict__ Wt_sum, float* __restrict__ bsum) {
    int i = blockIdx.x * blockDim.x + threadIdx.x;
    if (i < D * D) {
        int k = i >> 7, n = i & 127;
        int ti = n * D + k;
        Wt_adj[ti]    = f2bf(Wra[i]);
        Wt_g[ti]      = f2bf(Wrg[i]);
        Wt_t[ti]      = f2bf(Wrt[i]);
        Wt_root_t[ti] = f2bf(Wroot_t[i]);
        Wt_sum[ti]    = f2bf(Wroot_a[i] + Wroot_g[i]);
    }
    if (i < D) bsum[i] = ba[i] + bg[i];
}

// ---------------- bucket build ----------------
__global__ void fill_buckets(const int* __restrict__ src, const int* __restrict__ dst, int E,
                             int* __restrict__ cnt, int* __restrict__ buckets,
                             int* __restrict__ ovf, int* __restrict__ ovf_cnt) {
    int e = blockIdx.x * blockDim.x + threadIdx.x;
    if (e >= E) return;
    int d = dst[e];
    int p = atomicAdd(&cnt[d], 1);
    if (p < CAP) buckets[(long)d * CAP + p] = src[e];
    else         ovf[atomicAdd(ovf_cnt, 1)] = e;
}

// ---------------- pull-aggregate (bf16): agg[d] = sum y[src_e], no atomics ----------------
// one wave per dst row. MLP-optimized: two 32-lane halves each gather a DIFFERENT
// edge's source row (lane = uint2 = 4 cols), unrolled x2 -> 4 rows in flight/wave.
__launch_bounds__(256)
__global__ void pull_agg(const unsigned short* __restrict__ y,
                         const int* __restrict__ cnt, const int* __restrict__ buckets,
                         const int* __restrict__ src, const int* __restrict__ dst,
                         const int* __restrict__ ovf, const int* __restrict__ ovf_cnt,
                         unsigned short* __restrict__ agg, int N) {
    int wid = (int)(((long)blockIdx.x * blockDim.x + threadIdx.x) >> 6);
    int lane = threadIdx.x & 63;
    if (wid >= N) return;
    const int half = lane >> 5;          // 0: even edge of pair, 1: odd edge
    const int hl = lane & 31;            // column group: cols [hl*4 .. hl*4+3]
    const long colOff = (long)hl * 4;

    int m = cnt[wid];
    int mc = m > CAP ? CAP : m;
    int idx = (lane < mc) ? buckets[(long)wid * CAP + lane] : 0;

    float acc0 = 0.f, acc1 = 0.f, acc2 = 0.f, acc3 = 0.f;

    for (int j = 0; j < mc; j += 4) {
        int e0 = j + half;               // batch slot 0 (edges j, j+1)
        int e1 = j + 2 + half;           // batch slot 1 (edges j+2, j+3)
        int s0 = __shfl(idx, e0, 64);    // e_k <= CAP+2 < 64; inactive slots -> row 0 (valid addr)
        int s1 = __shfl(idx, e1, 64);
        uint2 r0 = *(const uint2*)(y + (long)s0 * D + colOff);
        uint2 r1 = *(const uint2*)(y + (long)s1 * D + colOff);
        if (e0 >= mc) { r0.x = 0u; r0.y = 0u; }   // branchless cndmask; bf16 0-bits == 0.0f
        if (e1 >= mc) { r1.x = 0u; r1.y = 0u; }
        acc0 += bf2f(r0.x & 0xffffu) + bf2f(r1.x & 0xffffu);
        acc1 += bf2f(r0.x >> 16)     + bf2f(r1.x >> 16);
        acc2 += bf2f(r0.y & 0xffffu) + bf2f(r1.y & 0xffffu);
        acc3 += bf2f(r0.y >> 16)     + bf2f(r1.y >> 16);
    }

    if (m > CAP) {                       // rare path: exact via overflow list scan
        int oc = *ovf_cnt;
        for (int i = 0; i < oc; ++i) {
            int e = ovf[i];
            if (dst[e] == wid && half == 0) {   // count once (halves are summed below)
                int s = src[e];
                uint2 r = *(const uint2*)(y + (long)s * D + colOff);
                acc0 += bf2f(r.x & 0xffffu);
                acc1 += bf2f(r.x >> 16);
                acc2 += bf2f(r.y & 0xffffu);
                acc3 += bf2f(r.y >> 16);
            }
        }
    }

    // combine the two halves (lane <-> lane+32)
    acc0 += __shfl_xor(acc0, 32, 64);
    acc1 += __shfl_xor(acc1, 32, 64);
    acc2 += __shfl_xor(acc2, 32, 64);
    acc3 += __shfl_xor(acc3, 32, 64);

    if (half == 0) {
        uint2 o;
        o.x = (unsigned int)f2bf(acc0) | ((unsigned int)f2bf(acc1) << 16);
        o.y = (unsigned int)f2bf(acc2) | ((unsigned int)f2bf(acc3) << 16);
        *(uint2*)(agg + (long)wid * D + colOff) = o;
    }
}

// ---------------- fused MFMA GEMM, no-LDS no-barrier, var+con merged ----------------
// out = sum_t A_t @ W_t + bias, + column stats.
// Rationale: A fragments have ZERO intra-block reuse (each consumed by one lane)
// -> load global->VGPR directly. W is 32KB/term and L2-resident -> B fragments
// read from L2 (~200cy, prefetchable). No barriers in the K-loop at all: waves
// free-run, latency hidden by ILP (10 loads in flight per ks) and TLP.
// var blocks [0,nbVar) (3 terms), con blocks [nbVar,nbVar+nbCon) (2 terms).
__launch_bounds__(256, 3)
__global__ void gemm_fused(int nbVar, int Nvar, int Ncon,
                           const unsigned short* __restrict__ Av0, const unsigned short* __restrict__ Wv0,
                           const unsigned short* __restrict__ Av1, const unsigned short* __restrict__ Wv1,
                           const unsigned short* __restrict__ Av2, const unsigned short* __restrict__ Wv2,
                           const unsigned short* __restrict__ Ac0, const unsigned short* __restrict__ Wc0,
                           const unsigned short* __restrict__ Ac1, const unsigned short* __restrict__ Wc1,
                           const float* __restrict__ biasV, const float* __restrict__ biasC,
                           float* __restrict__ outV, float* __restrict__ outC,
                           float* __restrict__ stats) {
    __shared__ float sstat[256];
    const int tx = threadIdx.x;
    sstat[tx] = 0.f;
    __syncthreads();

    const bool isVar = (int)blockIdx.x < nbVar;
    const int bid = isVar ? blockIdx.x : blockIdx.x - nbVar;
    const int N = isVar ? Nvar : Ncon;
    const float* bias = isVar ? biasV : biasC;
    float* out = isVar ? outV : outC;
    float* gsum = stats + (isVar ? 0 : 256);
    float* gsq = gsum + 128;

    const int wave = tx >> 6, lane = tx & 63;
    const int quad = lane >> 4, l16 = lane & 15;
    const int row0 = bid * 128 + wave * 32;

    long r0 = row0 + l16;      if (r0 >= N) r0 = N - 1;   // clamped tail; epilogue guards exactness
    long r1 = row0 + 16 + l16; if (r1 >= N) r1 = N - 1;

    f32x4 acc[2][8];
#pragma unroll
    for (int rt = 0; rt < 2; ++rt)
#pragma unroll
        for (int ct = 0; ct < 8; ++ct)
#pragma unroll
            for (int i = 0; i < 4; ++i) acc[rt][ct][i] = 0.f;

    auto term = [&](const unsigned short* __restrict__ A, const unsigned short* __restrict__ W) {
        const unsigned short* a0p = A + r0 * D + quad * 8;
        const unsigned short* a1p = A + r1 * D + quad * 8;
        const unsigned short* wp  = W + (long)l16 * D + quad * 8;
#pragma unroll
        for (int ks = 0; ks < 4; ++ks) {
            bf16x8 a0 = *(const bf16x8*)(a0p + ks * 32);
            bf16x8 a1 = *(const bf16x8*)(a1p + ks * 32);
            bf16x8 b[8];
#pragma unroll
            for (int ct = 0; ct < 8; ++ct)
                b[ct] = *(const bf16x8*)(wp + ct * 16 * D + ks * 32);
#pragma unroll
            for (int ct = 0; ct < 8; ++ct) {
                acc[0][ct] = __builtin_amdgcn_mfma_f32_16x16x32_bf16(a0, b[ct], acc[0][ct], 0, 0, 0);
                acc[1][ct] = __builtin_amdgcn_mfma_f32_16x16x32_bf16(a1, b[ct], acc[1][ct], 0, 0, 0);
            }
        }
    };

    if (isVar) { term(Av0, Wv0); term(Av1, Wv1); term(Av2, Wv2); }
    else       { term(Ac0, Wc0); term(Ac1, Wc1); }

    // epilogue: bias, store, per-column partial stats
    float bv[8];
#pragma unroll
    for (int ct = 0; ct < 8; ++ct) bv[ct] = bias[ct * 16 + l16];

    float psum[8], psq[8];
#pragma unroll
    for (int ct = 0; ct < 8; ++ct) { psum[ct] = 0.f; psq[ct] = 0.f; }

#pragma unroll
    for (int rt = 0; rt < 2; ++rt)
#pragma unroll
        for (int i = 0; i < 4; ++i) {
            int row = row0 + rt * 16 + quad * 4 + i;
            if (row < N) {
#pragma unroll
                for (int ct = 0; ct < 8; ++ct) {
                    float v = acc[rt][ct][i] + bv[ct];
                    out[(size_t)row * D + ct * 16 + l16] = v;
                    psum[ct] += v;
                    psq[ct] += v * v;
                }
            }
        }

    // quad-reduce (lanes l16, l16+16, l16+32, l16+48 hold same column) so each
    // sstat address is touched by ONE lane per wave instr -> no LDS atomic serialization
#pragma unroll
    for (int ct = 0; ct < 8; ++ct) {
        psum[ct] += __shfl_xor(psum[ct], 16, 64);
        psum[ct] += __shfl_xor(psum[ct], 32, 64);
        psq[ct]  += __shfl_xor(psq[ct], 16, 64);
        psq[ct]  += __shfl_xor(psq[ct], 32, 64);
    }
    if (quad == 0) {
#pragma unroll
        for (int ct = 0; ct < 8; ++ct) {
            atomicAdd(&sstat[ct * 16 + l16], psum[ct]);
            atomicAdd(&sstat[128 + ct * 16 + l16], psq[ct]);
        }
    }
    __syncthreads();
    if (tx < 128) {
        atomAddF(&gsum[tx], sstat[tx]);
        atomAddF(&gsq[tx], sstat[128 + tx]);
    }
}

// ---------------- stats -> scale/shift ----------------
__global__ void finalize_stats(const float* __restrict__ stats,
                               const float* __restrict__ wv, const float* __restrict__ bv, const float* __restrict__ msv,
                               const float* __restrict__ wc, const float* __restrict__ bc, const float* __restrict__ msc,
                               int Nvar, int Ncon,
                               float* __restrict__ scale_var, float* __restrict__ shift_var,
                               float* __restrict__ scale_con, float* __restrict__ shift_con) {
    int tx = threadIdx.x;
    if (tx < 128) {
        float n = (float)Nvar;
        float mu = stats[tx] / n;
        float ex2 = stats[128 + tx] / n;
        float ms = msv[tx];
        float var = ex2 - 2.f * ms * mu * mu + ms * ms * mu * mu;
        float istd = rsqrtf(var + 1e-5f);
        float sc = wv[tx] * istd;
        scale_var[tx] = sc;
        shift_var[tx] = bv[tx] - sc * ms * mu;
    } else if (tx < 256) {
        int t = tx - 128;
        float n = (float)Ncon;
        float mu = stats[256 + t] / n;
        float ex2 = stats[384 + t] / n;
        float ms = msc[t];
        float var = ex2 - 2.f * ms * mu * mu + ms * ms * mu * mu;
        float istd = rsqrtf(var + 1e-5f);
        float sc = wc[t] * istd;
        scale_con[t] = sc;
        shift_con[t] = bc[t] - sc * ms * mu;
    }
}

// ---------------- in-place normalize + relu ----------------
__global__ void norm_relu(float* __restrict__ buf,
                          const float* __restrict__ scale, const float* __restrict__ shift,
                          long nvec) {
    long i = (long)blockIdx.x * blockDim.x + threadIdx.x;
    if (i >= nvec) return;
    int q = ((int)i & 31) * 4;
    float4 v = *(float4*)(buf + i * 4);
    float4 o;
    o.x = fmaxf(0.f, v.x * scale[q + 0] + shift[q + 0]);
    o.y = fmaxf(0.f, v.y * scale[q + 1] + shift[q + 1]);
    o.z = fmaxf(0.f, v.z * scale[q + 2] + shift[q + 2]);
    o.w = fmaxf(0.f, v.w * scale[q + 3] + shift[q + 3]);
    *(float4*)(buf + i * 4) = o;
}

extern "C" void kernel_launch(void* const* d_in, const int* in_sizes, int n_in,
                              void* d_out, int out_size, void* d_ws, size_t ws_size,
                              hipStream_t stream) {
    const float* x_var = (const float*)d_in[0];
    const float* x_con = (const float*)d_in[1];
    const float* x_reg = (const float*)d_in[2];
    const int* src_adj = (const int*)d_in[3];
    const int* dst_adj = (const int*)d_in[4];
    const int* src_t   = (const int*)d_in[5];
    const int* dst_t   = (const int*)d_in[6];
    const int* src_g   = (const int*)d_in[7];
    const int* dst_g   = (const int*)d_in[8];
    const float* W_rel_adj  = (const float*)d_in[9];
    const float* b_adj      = (const float*)d_in[10];
    const float* W_root_adj = (const float*)d_in[11];
    const float* W_rel_t    = (const float*)d_in[12];
    const float* b_t        = (const float*)d_in[13];
    const float* W_root_t   = (const float*)d_in[14];
    const float* W_rel_g    = (const float*)d_in[15];
    const float* b_g        = (const float*)d_in[16];
    const float* W_root_g   = (const float*)d_in[17];
    const float* gnw_v  = (const float*)d_in[18];
    const float* gnb_v  = (const float*)d_in[19];
    const float* gnms_v = (const float*)d_in[20];
    const float* gnw_c  = (const float*)d_in[21];
    const float* gnb_c  = (const float*)d_in[22];
    const float* gnms_c = (const float*)d_in[23];

    const int Nvar = in_sizes[0] / D;
    const int Ncon = in_sizes[1] / D;
    const int Nreg = in_sizes[2] / D;
    const int Eadj = in_sizes[3];
    const int Et   = in_sizes[5];
    const int Eg   = in_sizes[7];
    const int Emax = Eadj > Et ? (Eadj > Eg ? Eadj : Eg) : (Et > Eg ? Et : Eg);

    // ---- workspace layout (large blocks first, all 256B-aligned) ----
    char* p = (char*)d_ws;
    unsigned short* xv_bf = (unsigned short*)p; p += (size_t)Nvar * D * 2;
    unsigned short* xc_bf = (unsigned short*)p; p += (size_t)Ncon * D * 2;
    unsigned short* xr_bf = (unsigned short*)p; p += (size_t)Nreg * D * 2;
    unsigned short* agg_adj = (unsigned short*)p; p += (size_t)Nvar * D * 2;
    unsigned short* agg_g   = (unsigned short*)p; p += (size_t)Nvar * D * 2;
    unsigned short* agg_t   = (unsigned short*)p; p += (size_t)Ncon * D * 2;
    int* buckets = (int*)p; p += (size_t)Nvar * CAP * 4;
    int* ovf     = (int*)p; p += (size_t)Emax * 4;
    int* cnt     = (int*)p; p += (size_t)Nvar * 4;
    unsigned short* Wt_adj    = (unsigned short*)p; p += D * D * 2;
    unsigned short* Wt_g      = (unsigned short*)p; p += D * D * 2;
    unsigned short* Wt_t      = (unsigned short*)p; p += D * D * 2;
    unsigned short* Wt_root_t = (unsigned short*)p; p += D * D * 2;
    unsigned short* Wt_sum    = (unsigned short*)p; p += D * D * 2;
    float* bsum  = (float*)p; p += D * 4;
    float* stats = (float*)p; p += 512 * 4;
    float* scale_var = (float*)p; p += D * 4;
    float* shift_var = (float*)p; p += D * 4;
    float* scale_con = (float*)p; p += D * 4;
    float* shift_con = (float*)p; p += D * 4;
    int* ovf_cnt = (int*)p; p += 256;

    float* out_var = (float*)d_out;
    float* out_con = out_var + (size_t)Nvar * D;

    hipMemsetAsync(stats, 0, 512 * sizeof(float), stream);
    prep_weights<<<64, 256, 0, stream>>>(W_rel_adj, W_rel_g, W_rel_t, W_root_t,
                                         W_root_adj, W_root_g, b_adj, b_g,
                                         Wt_adj, Wt_g, Wt_t, Wt_root_t, Wt_sum, bsum);

    cast_bf16<<<(int)(((long)Nvar * 32 + 255) / 256), 256, 0, stream>>>(x_var, xv_bf, (long)Nvar * 32);
    cast_bf16<<<(int)(((long)Ncon * 32 + 255) / 256), 256, 0, stream>>>(x_con, xc_bf, (long)Ncon * 32);
    cast_bf16<<<(int)(((long)Nreg * 32 + 255) / 256), 256, 0, stream>>>(x_reg, xr_bf, (long)Nreg * 32);

    struct G { const unsigned short* xs; const int* src; const int* dst; int E; int Ndst; unsigned short* agg; };
    G graphs[3] = {
        { xv_bf, src_adj, dst_adj, Eadj, Nvar, agg_adj },
        { xr_bf, src_g,   dst_g,   Eg,   Nvar, agg_g   },
        { xv_bf, src_t,   dst_t,   Et,   Ncon, agg_t   },
    };

    for (int gi = 0; gi < 3; ++gi) {
        G& g = graphs[gi];
        hipMemsetAsync(cnt, 0, (size_t)g.Ndst * sizeof(int), stream);
        hipMemsetAsync(ovf_cnt, 0, sizeof(int), stream);
        fill_buckets<<<(g.E + 255) / 256, 256, 0, stream>>>(g.src, g.dst, g.E, cnt, buckets, ovf, ovf_cnt);
        long T = (long)g.Ndst * 64;
        pull_agg<<<(int)((T + 255) / 256), 256, 0, stream>>>(g.xs, cnt, buckets,
                                                             g.src, g.dst, ovf, ovf_cnt,
                                                             g.agg, g.Ndst);
    }

    const int nbVar = (Nvar + 127) / 128;
    const int nbCon = (Ncon + 127) / 128;
    gemm_fused<<<nbVar + nbCon, 256, 0, stream>>>(nbVar, Nvar, Ncon,
        agg_adj, Wt_adj, agg_g, Wt_g, xv_bf, Wt_sum,
        agg_t, Wt_t, xc_bf, Wt_root_t,
        bsum, b_t, out_var, out_con, stats);

    finalize_stats<<<1, 256, 0, stream>>>(stats,
        gnw_v, gnb_v, gnms_v, gnw_c, gnb_c, gnms_c,
        Nvar, Ncon, scale_var, shift_var, scale_con, shift_con);

    {
        long nvec = (long)Nvar * 32;
        norm_relu<<<(int)((nvec + 255) / 256), 256, 0, stream>>>(out_var, scale_var, shift_var, nvec);
    }
    {
        long nvec = (long)Ncon * 32;
        norm_relu<<<(int)((nvec + 255) / 256), 256, 0, stream>>>(out_con, scale_con, shift_con, nvec);
    }
}